// Round 3
// baseline (610.106 us; speedup 1.0000x reference)
//
#include <hip/hip_runtime.h>
#include <hip/hip_fp16.h>
#include <math.h>

#define FEAT 128
#define OUTF 384
#define NRBF 20

typedef float f32x2 __attribute__((ext_vector_type(2)));
typedef float f32x4 __attribute__((ext_vector_type(4)));

// Detect whether nbrs buffer is int64 (little-endian: odd int32 words are the
// high halves, all zero since indices < 50000) or genuine int32 pairs.
__device__ __forceinline__ int nbrs_is_i64(const int* nb) {
    int nz = 0;
#pragma unroll
    for (int i = 1; i < 64; i += 2) nz |= nb[i];
    return nz == 0;
}

// Computes PHI[row] = silu(src_row @ W1 + b1) @ W2 + b2 for 64 rows per block.
// GATHER=false: src row i = s_j[i]      (node mode)
// GATHER=true : src row i = s_j[nbrs[i,1]] (direct fallback mode)
// HALF_OUT: store rows as fp16 (node mode) vs fp32 (fallback, dst = d_out).
template <bool GATHER, bool HALF_OUT>
__global__ __launch_bounds__(256) void phi_kernel(
    const float* __restrict__ s_j, const int* __restrict__ nbrs,
    const float* __restrict__ W1, const float* __restrict__ b1,
    const float* __restrict__ W2, const float* __restrict__ b2,
    void* __restrict__ dst_v, int M)
{
    __shared__ __align__(16) float st[FEAT][66]; // transposed tile [k][row]; reused for h
    const int t = threadIdx.x;
    const int base = blockIdx.x * 64;

    int i64f = 0;
    if (GATHER) i64f = nbrs_is_i64(nbrs);

    // stage s tile (transposed). idx consecutive -> k consecutive -> coalesced.
    for (int idx = t; idx < 64 * FEAT; idx += 256) {
        int n = idx >> 7, k = idx & 127;
        int row = base + n;
        float v = 0.f;
        if (row < M) {
            int src = GATHER ? (i64f ? nbrs[4 * (size_t)row + 2] : nbrs[2 * (size_t)row + 1])
                             : row;
            v = s_j[(size_t)src * FEAT + k];
        }
        st[k][n] = v;
    }
    __syncthreads();

    const int cg = t & 31;  // 32 column groups of 4
    const int rg = t >> 5;  // 8 row groups of 8
    const int c0 = cg * 4;
    const int r0 = rg * 8;

    float acc[8][4];
    // ---- h = silu(s @ W1 + b1), thread tile 8 rows x 4 cols ----
    {
        float4 b = *(const float4*)(b1 + c0);
#pragma unroll
        for (int i = 0; i < 8; i++) { acc[i][0] = b.x; acc[i][1] = b.y; acc[i][2] = b.z; acc[i][3] = b.w; }
        for (int k = 0; k < FEAT; k++) {
            float4 w = *(const float4*)(W1 + (size_t)k * FEAT + c0);
            float2 sa = *(const float2*)(&st[k][r0]);
            float2 sb = *(const float2*)(&st[k][r0 + 2]);
            float2 sc = *(const float2*)(&st[k][r0 + 4]);
            float2 sd = *(const float2*)(&st[k][r0 + 6]);
            float sv[8] = {sa.x, sa.y, sb.x, sb.y, sc.x, sc.y, sd.x, sd.y};
#pragma unroll
            for (int i = 0; i < 8; i++) {
                acc[i][0] += sv[i] * w.x; acc[i][1] += sv[i] * w.y;
                acc[i][2] += sv[i] * w.z; acc[i][3] += sv[i] * w.w;
            }
        }
    }
    __syncthreads();  // all reads of st done before overwriting with h
    // silu + store h transposed into the same LDS buffer
#pragma unroll
    for (int i = 0; i < 8; i++)
#pragma unroll
        for (int j = 0; j < 4; j++) {
            float h = acc[i][j];
            h = h * __frcp_rn(1.f + __expf(-h));
            st[c0 + j][r0 + i] = h;
        }
    __syncthreads();

    // ---- phi = h @ W2 + b2, 3 chunks of 128 cols ----
    for (int ch = 0; ch < 3; ch++) {
        const int oc = ch * 128 + c0;
        float4 b = *(const float4*)(b2 + oc);
#pragma unroll
        for (int i = 0; i < 8; i++) { acc[i][0] = b.x; acc[i][1] = b.y; acc[i][2] = b.z; acc[i][3] = b.w; }
        for (int k = 0; k < FEAT; k++) {
            float4 w = *(const float4*)(W2 + (size_t)k * OUTF + oc);
            float2 ha = *(const float2*)(&st[k][r0]);
            float2 hb = *(const float2*)(&st[k][r0 + 2]);
            float2 hc = *(const float2*)(&st[k][r0 + 4]);
            float2 hd = *(const float2*)(&st[k][r0 + 6]);
            float hv[8] = {ha.x, ha.y, hb.x, hb.y, hc.x, hc.y, hd.x, hd.y};
#pragma unroll
            for (int i = 0; i < 8; i++) {
                acc[i][0] += hv[i] * w.x; acc[i][1] += hv[i] * w.y;
                acc[i][2] += hv[i] * w.z; acc[i][3] += hv[i] * w.w;
            }
        }
#pragma unroll
        for (int i = 0; i < 8; i++) {
            int row = base + r0 + i;
            if (row < M) {
                if (HALF_OUT) {
                    __half2* p = (__half2*)((__half*)dst_v + (size_t)row * OUTF + oc);
                    p[0] = __floats2half2_rn(acc[i][0], acc[i][1]);
                    p[1] = __floats2half2_rn(acc[i][2], acc[i][3]);
                } else {
                    float4 o = {acc[i][0], acc[i][1], acc[i][2], acc[i][3]};
                    *(float4*)((float*)dst_v + (size_t)row * OUTF + oc) = o;
                }
            }
        }
    }
}

// Per edge: out[e] = phi_row * (rbf(dist[e]) @ Wd + bd)
// 192 threads per edge, each owns 2 output cols (wd slice = 40 VGPRs ->
// high occupancy for gather latency hiding). Two edges in flight per thread.
// rbf via Chebyshev recurrence: sin((n+1)x) = 2cos(x) sin(nx) - sin((n-1)x).
// FP16PHI: phi rows stored fp16 (node mode, 4B/lane gather).
// NOTE: phi/out may alias (fallback mode) -> no __restrict__ on them.
template <bool FP16PHI>
__global__ __launch_bounds__(384, 5) void edge_kernel(
    const float* __restrict__ dist, const int* __restrict__ nbrs,
    const void* phi_v, const float* __restrict__ Wd,
    const float* __restrict__ bd, float* out,
    int E, int gather)
{
    const int g = threadIdx.x / 192;   // edge-pair slot within block
    const int q = threadIdx.x % 192;   // column-pair id
    const int c0 = q * 2;

    f32x2 wd[NRBF];
#pragma unroll
    for (int k = 0; k < NRBF; k++) wd[k] = *(const f32x2*)(Wd + (size_t)k * OUTF + c0);
    f32x2 bdr = *(const f32x2*)(bd + c0);

    int i64f = gather ? nbrs_is_i64(nbrs) : 0;
    const float kx = (float)(M_PI / 5.0);
    const long long stride = (long long)gridDim.x * 4;

    for (long long e = (long long)blockIdx.x * 4 + g * 2; e < E; e += stride) {
        const bool has1 = (e + 1 < E);
        float d0 = __builtin_nontemporal_load(dist + e);
        float d1 = has1 ? __builtin_nontemporal_load(dist + e + 1) : 1.f;
        long long r0, r1;
        if (gather) {
            r0 = i64f ? nbrs[4 * e + 2] : nbrs[2 * e + 1];
            r1 = has1 ? (i64f ? nbrs[4 * e + 6] : nbrs[2 * e + 3]) : r0;
        } else { r0 = e; r1 = has1 ? e + 1 : r0; }

        // issue both gathers before the recurrences
        f32x2 p0, p1;
        if (FP16PHI) {
            const __half2* ph = (const __half2*)phi_v;
            __half2 v0 = ph[r0 * 192 + q];
            __half2 v1 = ph[r1 * 192 + q];
            float2 f0 = __half22float2(v0);
            float2 f1 = __half22float2(v1);
            p0 = (f32x2){f0.x, f0.y};
            p1 = (f32x2){f1.x, f1.y};
        } else {
            const float* pf = (const float*)phi_v;
            p0 = *(const f32x2*)(pf + r0 * OUTF + c0);
            p1 = *(const f32x2*)(pf + r1 * OUTF + c0);
        }

        float x0 = d0 * kx, x1 = d1 * kx;
        float s0 = __sinf(x0), cc0 = __cosf(x0);
        float s1 = __sinf(x1), cc1 = __cosf(x1);
        float t0 = 2.f * cc0, t1 = 2.f * cc1;
        float sp0 = 0.f, sc0 = s0;
        float sp1 = 0.f, sc1 = s1;
        f32x2 a0 = {0.f, 0.f};
        f32x2 a1 = {0.f, 0.f};
#pragma unroll
        for (int n = 0; n < NRBF; n++) {
            a0 += sc0 * wd[n];
            a1 += sc1 * wd[n];
            float n0 = t0 * sc0 - sp0; sp0 = sc0; sc0 = n0;
            float n1 = t1 * sc1 - sp1; sp1 = sc1; sc1 = n1;
        }
        float rd0 = __frcp_rn(d0), rd1 = __frcp_rn(d1);
        f32x2 o0 = p0 * (a0 * rd0 + bdr);
        __builtin_nontemporal_store(o0, (f32x2*)(out + e * OUTF + c0));
        if (has1) {
            f32x2 o1 = p1 * (a1 * rd1 + bdr);
            __builtin_nontemporal_store(o1, (f32x2*)(out + (e + 1) * OUTF + c0));
        }
    }
}

extern "C" void kernel_launch(void* const* d_in, const int* in_sizes, int n_in,
                              void* d_out, int out_size, void* d_ws, size_t ws_size,
                              hipStream_t stream)
{
    const float* s_j  = (const float*)d_in[0];
    const float* dist = (const float*)d_in[1];
    const int*   nbrs = (const int*)d_in[2];
    const float* W1   = (const float*)d_in[3];
    const float* b1   = (const float*)d_in[4];
    const float* W2   = (const float*)d_in[5];
    const float* b2   = (const float*)d_in[6];
    const float* Wd   = (const float*)d_in[7];
    const float* bd   = (const float*)d_in[8];
    float* out = (float*)d_out;

    const int N = in_sizes[0] / FEAT;
    const int E = in_sizes[1];
    if (E <= 0) return;

    const size_t phi_bytes = (size_t)N * OUTF * sizeof(__half);
    int egrid = (E + 3) / 4;
    if (egrid > 2048) egrid = 2048;

    if (ws_size >= phi_bytes) {
        // node-level precompute: PHI (N x 384, fp16) in workspace, then edge scale
        dim3 gA((N + 63) / 64);
        phi_kernel<false, true><<<gA, 256, 0, stream>>>(s_j, nbrs, W1, b1, W2, b2, d_ws, N);
        edge_kernel<true><<<egrid, 384, 0, stream>>>(dist, nbrs, d_ws, Wd, bd, out, E, 1);
    } else {
        // fallback: per-edge phi (fp32) directly into d_out, then scale in place
        dim3 gA((E + 63) / 64);
        phi_kernel<true, false><<<gA, 256, 0, stream>>>(s_j, nbrs, W1, b1, W2, b2, d_out, E);
        edge_kernel<false><<<egrid, 384, 0, stream>>>(dist, nbrs, d_out, Wd, bd, out, E, 0);
    }
}

// Round 4
// 506.171 us; speedup vs baseline: 1.2053x; 1.2053x over previous
//
#include <hip/hip_runtime.h>
#include <math.h>

#define FEAT 128
#define OUTF 384
#define NRBF 20

typedef float f32x2 __attribute__((ext_vector_type(2)));
typedef float f32x4 __attribute__((ext_vector_type(4)));
typedef _Float16 f16x4 __attribute__((ext_vector_type(4)));

// Detect whether nbrs buffer is int64 (little-endian: odd int32 words are the
// high halves, all zero since indices < 50000) or genuine int32 pairs.
__device__ __forceinline__ int nbrs_is_i64(const int* nb) {
    int nz = 0;
#pragma unroll
    for (int i = 1; i < 64; i += 2) nz |= nb[i];
    return nz == 0;
}

// Computes PHI[row] = silu(src_row @ W1 + b1) @ W2 + b2 for 64 rows per block.
// GATHER=false: src row i = s_j[i]      (node mode)
// GATHER=true : src row i = s_j[nbrs[i,1]] (direct fallback mode)
// HALF_OUT: store rows as fp16 (node mode) vs fp32 (fallback, dst = d_out).
template <bool GATHER, bool HALF_OUT>
__global__ __launch_bounds__(256) void phi_kernel(
    const float* __restrict__ s_j, const int* __restrict__ nbrs,
    const float* __restrict__ W1, const float* __restrict__ b1,
    const float* __restrict__ W2, const float* __restrict__ b2,
    void* __restrict__ dst_v, int M)
{
    __shared__ __align__(16) float st[FEAT][66]; // transposed tile [k][row]; reused for h
    const int t = threadIdx.x;
    const int base = blockIdx.x * 64;

    int i64f = 0;
    if (GATHER) i64f = nbrs_is_i64(nbrs);

    // stage s tile (transposed). idx consecutive -> k consecutive -> coalesced.
    for (int idx = t; idx < 64 * FEAT; idx += 256) {
        int n = idx >> 7, k = idx & 127;
        int row = base + n;
        float v = 0.f;
        if (row < M) {
            int src = GATHER ? (i64f ? nbrs[4 * (size_t)row + 2] : nbrs[2 * (size_t)row + 1])
                             : row;
            v = s_j[(size_t)src * FEAT + k];
        }
        st[k][n] = v;
    }
    __syncthreads();

    const int cg = t & 31;  // 32 column groups of 4
    const int rg = t >> 5;  // 8 row groups of 8
    const int c0 = cg * 4;
    const int r0 = rg * 8;

    float acc[8][4];
    // ---- h = silu(s @ W1 + b1), thread tile 8 rows x 4 cols ----
    {
        float4 b = *(const float4*)(b1 + c0);
#pragma unroll
        for (int i = 0; i < 8; i++) { acc[i][0] = b.x; acc[i][1] = b.y; acc[i][2] = b.z; acc[i][3] = b.w; }
        for (int k = 0; k < FEAT; k++) {
            float4 w = *(const float4*)(W1 + (size_t)k * FEAT + c0);
            float2 sa = *(const float2*)(&st[k][r0]);
            float2 sb = *(const float2*)(&st[k][r0 + 2]);
            float2 sc = *(const float2*)(&st[k][r0 + 4]);
            float2 sd = *(const float2*)(&st[k][r0 + 6]);
            float sv[8] = {sa.x, sa.y, sb.x, sb.y, sc.x, sc.y, sd.x, sd.y};
#pragma unroll
            for (int i = 0; i < 8; i++) {
                acc[i][0] += sv[i] * w.x; acc[i][1] += sv[i] * w.y;
                acc[i][2] += sv[i] * w.z; acc[i][3] += sv[i] * w.w;
            }
        }
    }
    __syncthreads();  // all reads of st done before overwriting with h
    // silu + store h transposed into the same LDS buffer
#pragma unroll
    for (int i = 0; i < 8; i++)
#pragma unroll
        for (int j = 0; j < 4; j++) {
            float h = acc[i][j];
            h = h * __frcp_rn(1.f + __expf(-h));
            st[c0 + j][r0 + i] = h;
        }
    __syncthreads();

    // ---- phi = h @ W2 + b2, 3 chunks of 128 cols ----
    for (int ch = 0; ch < 3; ch++) {
        const int oc = ch * 128 + c0;
        float4 b = *(const float4*)(b2 + oc);
#pragma unroll
        for (int i = 0; i < 8; i++) { acc[i][0] = b.x; acc[i][1] = b.y; acc[i][2] = b.z; acc[i][3] = b.w; }
        for (int k = 0; k < FEAT; k++) {
            float4 w = *(const float4*)(W2 + (size_t)k * OUTF + oc);
            float2 ha = *(const float2*)(&st[k][r0]);
            float2 hb = *(const float2*)(&st[k][r0 + 2]);
            float2 hc = *(const float2*)(&st[k][r0 + 4]);
            float2 hd = *(const float2*)(&st[k][r0 + 6]);
            float hv[8] = {ha.x, ha.y, hb.x, hb.y, hc.x, hc.y, hd.x, hd.y};
#pragma unroll
            for (int i = 0; i < 8; i++) {
                acc[i][0] += hv[i] * w.x; acc[i][1] += hv[i] * w.y;
                acc[i][2] += hv[i] * w.z; acc[i][3] += hv[i] * w.w;
            }
        }
#pragma unroll
        for (int i = 0; i < 8; i++) {
            int row = base + r0 + i;
            if (row < M) {
                if (HALF_OUT) {
                    f16x4 o = {(_Float16)acc[i][0], (_Float16)acc[i][1],
                               (_Float16)acc[i][2], (_Float16)acc[i][3]};
                    *(f16x4*)((_Float16*)dst_v + (size_t)row * OUTF + oc) = o;
                } else {
                    float4 o = {acc[i][0], acc[i][1], acc[i][2], acc[i][3]};
                    *(float4*)((float*)dst_v + (size_t)row * OUTF + oc) = o;
                }
            }
        }
    }
}

// Per edge: out[e] = phi_row * (rbf(dist[e]) @ Wd + bd)
// 96 threads per edge, each owns 4 output cols; Wd column slice lives in VGPRs.
// Two consecutive edges per thread per iteration (2 gathers in flight).
// rbf via Chebyshev recurrence: sin((n+1)x) = 2cos(x) sin(nx) - sin((n-1)x).
// FP16PHI: phi rows stored fp16 (node mode, 8 B/lane gather, 768 B rows).
// out written with 16 B NON-TEMPORAL stores (bypass L2 alloc; keep caches
// for the gather table). NOTE: phi/out may alias (fallback) -> no __restrict__.
template <bool FP16PHI>
__global__ __launch_bounds__(384, 3) void edge_kernel(
    const float* __restrict__ dist, const int* __restrict__ nbrs,
    const void* phi_v, const float* __restrict__ Wd,
    const float* __restrict__ bd, float* out,
    int E, int gather)
{
    const int g = threadIdx.x / 96;
    const int q = threadIdx.x % 96;
    const int c0 = q * 4;

    f32x4 wd[NRBF];
#pragma unroll
    for (int k = 0; k < NRBF; k++) wd[k] = *(const f32x4*)(Wd + (size_t)k * OUTF + c0);
    f32x4 bdr = *(const f32x4*)(bd + c0);

    int i64f = gather ? nbrs_is_i64(nbrs) : 0;
    const float kx = (float)(M_PI / 5.0);
    const long long stride = (long long)gridDim.x * 8;

    for (long long e = (long long)blockIdx.x * 8 + g * 2; e < E; e += stride) {
        const bool has1 = (e + 1 < E);
        float d0 = __builtin_nontemporal_load(dist + e);
        float d1 = has1 ? __builtin_nontemporal_load(dist + e + 1) : 1.f;
        long long r0, r1;
        if (gather) {
            r0 = i64f ? nbrs[4 * e + 2] : nbrs[2 * e + 1];
            r1 = has1 ? (i64f ? nbrs[4 * e + 6] : nbrs[2 * e + 3]) : r0;
        } else { r0 = e; r1 = has1 ? e + 1 : r0; }

        // issue both gathers before the recurrences
        f32x4 p0, p1;
        if (FP16PHI) {
            const _Float16* ph = (const _Float16*)phi_v;
            f16x4 h0 = *(const f16x4*)(ph + r0 * OUTF + c0);
            f16x4 h1 = *(const f16x4*)(ph + r1 * OUTF + c0);
            p0 = (f32x4){(float)h0.x, (float)h0.y, (float)h0.z, (float)h0.w};
            p1 = (f32x4){(float)h1.x, (float)h1.y, (float)h1.z, (float)h1.w};
        } else {
            const float* pf = (const float*)phi_v;
            p0 = *(const f32x4*)(pf + r0 * OUTF + c0);
            p1 = *(const f32x4*)(pf + r1 * OUTF + c0);
        }

        float x0 = d0 * kx, x1 = d1 * kx;
        float s0 = __sinf(x0), cc0 = __cosf(x0);
        float s1 = __sinf(x1), cc1 = __cosf(x1);
        float t0 = 2.f * cc0, t1 = 2.f * cc1;
        float sp0 = 0.f, sc0 = s0;
        float sp1 = 0.f, sc1 = s1;
        f32x4 a0 = {0.f, 0.f, 0.f, 0.f};
        f32x4 a1 = {0.f, 0.f, 0.f, 0.f};
#pragma unroll
        for (int n = 0; n < NRBF; n++) {
            a0 += sc0 * wd[n];
            a1 += sc1 * wd[n];
            float n0 = t0 * sc0 - sp0; sp0 = sc0; sc0 = n0;
            float n1 = t1 * sc1 - sp1; sp1 = sc1; sc1 = n1;
        }
        float rd0 = __frcp_rn(d0), rd1 = __frcp_rn(d1);
        f32x4 o0 = p0 * (a0 * rd0 + bdr);
        __builtin_nontemporal_store(o0, (f32x4*)(out + e * OUTF + c0));
        if (has1) {
            f32x4 o1 = p1 * (a1 * rd1 + bdr);
            __builtin_nontemporal_store(o1, (f32x4*)(out + (e + 1) * OUTF + c0));
        }
    }
}

extern "C" void kernel_launch(void* const* d_in, const int* in_sizes, int n_in,
                              void* d_out, int out_size, void* d_ws, size_t ws_size,
                              hipStream_t stream)
{
    const float* s_j  = (const float*)d_in[0];
    const float* dist = (const float*)d_in[1];
    const int*   nbrs = (const int*)d_in[2];
    const float* W1   = (const float*)d_in[3];
    const float* b1   = (const float*)d_in[4];
    const float* W2   = (const float*)d_in[5];
    const float* b2   = (const float*)d_in[6];
    const float* Wd   = (const float*)d_in[7];
    const float* bd   = (const float*)d_in[8];
    float* out = (float*)d_out;

    const int N = in_sizes[0] / FEAT;
    const int E = in_sizes[1];
    if (E <= 0) return;

    const size_t phi_bytes = (size_t)N * OUTF * sizeof(_Float16);
    int egrid = (E + 7) / 8;
    if (egrid > 2048) egrid = 2048;

    if (ws_size >= phi_bytes) {
        // node-level precompute: PHI (N x 384, fp16) in workspace, then edge scale
        dim3 gA((N + 63) / 64);
        phi_kernel<false, true><<<gA, 256, 0, stream>>>(s_j, nbrs, W1, b1, W2, b2, d_ws, N);
        edge_kernel<true><<<egrid, 384, 0, stream>>>(dist, nbrs, d_ws, Wd, bd, out, E, 1);
    } else {
        // fallback: per-edge phi (fp32) directly into d_out, then scale in place
        dim3 gA((E + 63) / 64);
        phi_kernel<true, false><<<gA, 256, 0, stream>>>(s_j, nbrs, W1, b1, W2, b2, d_out, E);
        edge_kernel<false><<<egrid, 384, 0, stream>>>(dist, nbrs, d_out, Wd, bd, out, E, 0);
    }
}

// Round 5
// 372.333 us; speedup vs baseline: 1.6386x; 1.3595x over previous
//
#include <hip/hip_runtime.h>
#include <math.h>

#define FEAT 128
#define OUTF 384
#define NRBF 20

typedef float f32x2 __attribute__((ext_vector_type(2)));
typedef float f32x4 __attribute__((ext_vector_type(4)));
typedef _Float16 f16x4 __attribute__((ext_vector_type(4)));

// Detect whether nbrs buffer is int64 (little-endian: odd int32 words are the
// high halves, all zero since indices < 50000) or genuine int32 pairs.
__device__ __forceinline__ int nbrs_is_i64(const int* nb) {
    int nz = 0;
#pragma unroll
    for (int i = 1; i < 64; i += 2) nz |= nb[i];
    return nz == 0;
}

// Computes PHI[row] = silu(src_row @ W1 + b1) @ W2 + b2 for 64 rows per block.
// GATHER=false: src row i = s_j[i]      (node mode)
// GATHER=true : src row i = s_j[nbrs[i,1]] (direct fallback mode)
// HALF_OUT: store rows as fp16 (node mode) vs fp32 (fallback, dst = d_out).
template <bool GATHER, bool HALF_OUT>
__global__ __launch_bounds__(256) void phi_kernel(
    const float* __restrict__ s_j, const int* __restrict__ nbrs,
    const float* __restrict__ W1, const float* __restrict__ b1,
    const float* __restrict__ W2, const float* __restrict__ b2,
    void* __restrict__ dst_v, int M)
{
    __shared__ __align__(16) float st[FEAT][66]; // transposed tile [k][row]; reused for h
    const int t = threadIdx.x;
    const int base = blockIdx.x * 64;

    int i64f = 0;
    if (GATHER) i64f = nbrs_is_i64(nbrs);

    // stage s tile (transposed). idx consecutive -> k consecutive -> coalesced.
    for (int idx = t; idx < 64 * FEAT; idx += 256) {
        int n = idx >> 7, k = idx & 127;
        int row = base + n;
        float v = 0.f;
        if (row < M) {
            int src = GATHER ? (i64f ? nbrs[4 * (size_t)row + 2] : nbrs[2 * (size_t)row + 1])
                             : row;
            v = s_j[(size_t)src * FEAT + k];
        }
        st[k][n] = v;
    }
    __syncthreads();

    const int cg = t & 31;  // 32 column groups of 4
    const int rg = t >> 5;  // 8 row groups of 8
    const int c0 = cg * 4;
    const int r0 = rg * 8;

    float acc[8][4];
    // ---- h = silu(s @ W1 + b1), thread tile 8 rows x 4 cols ----
    {
        float4 b = *(const float4*)(b1 + c0);
#pragma unroll
        for (int i = 0; i < 8; i++) { acc[i][0] = b.x; acc[i][1] = b.y; acc[i][2] = b.z; acc[i][3] = b.w; }
#pragma unroll 4
        for (int k = 0; k < FEAT; k++) {
            float4 w = *(const float4*)(W1 + (size_t)k * FEAT + c0);
            float2 sa = *(const float2*)(&st[k][r0]);
            float2 sb = *(const float2*)(&st[k][r0 + 2]);
            float2 sc = *(const float2*)(&st[k][r0 + 4]);
            float2 sd = *(const float2*)(&st[k][r0 + 6]);
            float sv[8] = {sa.x, sa.y, sb.x, sb.y, sc.x, sc.y, sd.x, sd.y};
#pragma unroll
            for (int i = 0; i < 8; i++) {
                acc[i][0] += sv[i] * w.x; acc[i][1] += sv[i] * w.y;
                acc[i][2] += sv[i] * w.z; acc[i][3] += sv[i] * w.w;
            }
        }
    }
    __syncthreads();  // all reads of st done before overwriting with h
    // silu + store h transposed into the same LDS buffer
#pragma unroll
    for (int i = 0; i < 8; i++)
#pragma unroll
        for (int j = 0; j < 4; j++) {
            float h = acc[i][j];
            h = h * __frcp_rn(1.f + __expf(-h));
            st[c0 + j][r0 + i] = h;
        }
    __syncthreads();

    // ---- phi = h @ W2 + b2, 3 chunks of 128 cols ----
    for (int ch = 0; ch < 3; ch++) {
        const int oc = ch * 128 + c0;
        float4 b = *(const float4*)(b2 + oc);
#pragma unroll
        for (int i = 0; i < 8; i++) { acc[i][0] = b.x; acc[i][1] = b.y; acc[i][2] = b.z; acc[i][3] = b.w; }
#pragma unroll 4
        for (int k = 0; k < FEAT; k++) {
            float4 w = *(const float4*)(W2 + (size_t)k * OUTF + oc);
            float2 ha = *(const float2*)(&st[k][r0]);
            float2 hb = *(const float2*)(&st[k][r0 + 2]);
            float2 hc = *(const float2*)(&st[k][r0 + 4]);
            float2 hd = *(const float2*)(&st[k][r0 + 6]);
            float hv[8] = {ha.x, ha.y, hb.x, hb.y, hc.x, hc.y, hd.x, hd.y};
#pragma unroll
            for (int i = 0; i < 8; i++) {
                acc[i][0] += hv[i] * w.x; acc[i][1] += hv[i] * w.y;
                acc[i][2] += hv[i] * w.z; acc[i][3] += hv[i] * w.w;
            }
        }
#pragma unroll
        for (int i = 0; i < 8; i++) {
            int row = base + r0 + i;
            if (row < M) {
                if (HALF_OUT) {
                    f16x4 o = {(_Float16)acc[i][0], (_Float16)acc[i][1],
                               (_Float16)acc[i][2], (_Float16)acc[i][3]};
                    *(f16x4*)((_Float16*)dst_v + (size_t)row * OUTF + oc) = o;
                } else {
                    float4 o = {acc[i][0], acc[i][1], acc[i][2], acc[i][3]};
                    *(float4*)((float*)dst_v + (size_t)row * OUTF + oc) = o;
                }
            }
        }
    }
}

// Per edge: out[e] = phi_row * (rbf(dist[e]) @ Wd + bd)
// 96 threads per edge, each owns 4 output cols; Wd column slice lives in VGPRs.
// FOUR consecutive edges per thread per iteration: 4 gathers in flight and
// 4 independent 20-step sin-recurrence chains (~560 cy of latency cover).
// rbf via Chebyshev recurrence: sin((n+1)x) = 2cos(x) sin(nx) - sin((n-1)x).
// FP16PHI: phi rows stored fp16 (node mode, 8 B/lane gather, 768 B rows).
// out written with 16 B NON-TEMPORAL stores; dist/nbrs use plain cached loads.
// NOTE: phi/out may alias (fallback) -> no __restrict__.
template <bool FP16PHI>
__global__ __launch_bounds__(384, 3) void edge_kernel(
    const float* __restrict__ dist, const int* __restrict__ nbrs,
    const void* phi_v, const float* __restrict__ Wd,
    const float* __restrict__ bd, float* out,
    int E, int gather)
{
    const int g = threadIdx.x / 96;
    const int q = threadIdx.x % 96;
    const int c0 = q * 4;

    f32x4 wd[NRBF];
#pragma unroll
    for (int k = 0; k < NRBF; k++) wd[k] = *(const f32x4*)(Wd + (size_t)k * OUTF + c0);
    f32x4 bdr = *(const f32x4*)(bd + c0);

    int i64f = gather ? nbrs_is_i64(nbrs) : 0;
    const float kx = (float)(M_PI / 5.0);
    const long long stride = (long long)gridDim.x * 16;

    for (long long e = ((long long)blockIdx.x * 4 + g) * 4; e < E; e += stride) {
        float d[4];
        long long r[4];
#pragma unroll
        for (int j = 0; j < 4; j++) {
            long long ej = e + j; if (ej >= E) ej = E - 1;  // clamp (stores guarded)
            d[j] = dist[ej];
            r[j] = gather ? (long long)(i64f ? nbrs[4 * ej + 2] : nbrs[2 * ej + 1]) : ej;
        }
        // issue all 4 gathers before the recurrences
        f32x4 p[4];
#pragma unroll
        for (int j = 0; j < 4; j++) {
            if (FP16PHI) {
                const _Float16* ph = (const _Float16*)phi_v;
                f16x4 h = *(const f16x4*)(ph + r[j] * OUTF + c0);
                p[j] = (f32x4){(float)h.x, (float)h.y, (float)h.z, (float)h.w};
            } else {
                const float* pf = (const float*)phi_v;
                p[j] = *(const f32x4*)(pf + r[j] * OUTF + c0);
            }
        }

        float t2[4], sp[4], sc[4];
#pragma unroll
        for (int j = 0; j < 4; j++) {
            float x = d[j] * kx;
            sc[j] = __sinf(x);
            t2[j] = 2.f * __cosf(x);
            sp[j] = 0.f;
        }
        f32x4 a[4];
#pragma unroll
        for (int j = 0; j < 4; j++) a[j] = (f32x4){0.f, 0.f, 0.f, 0.f};
#pragma unroll
        for (int n = 0; n < NRBF; n++) {
#pragma unroll
            for (int j = 0; j < 4; j++) {
                a[j] += sc[j] * wd[n];
                float nx = t2[j] * sc[j] - sp[j]; sp[j] = sc[j]; sc[j] = nx;
            }
        }
#pragma unroll
        for (int j = 0; j < 4; j++) {
            if (e + j < E) {
                f32x4 o = p[j] * (a[j] * __frcp_rn(d[j]) + bdr);
                __builtin_nontemporal_store(o, (f32x4*)(out + (e + j) * OUTF + c0));
            }
        }
    }
}

extern "C" void kernel_launch(void* const* d_in, const int* in_sizes, int n_in,
                              void* d_out, int out_size, void* d_ws, size_t ws_size,
                              hipStream_t stream)
{
    const float* s_j  = (const float*)d_in[0];
    const float* dist = (const float*)d_in[1];
    const int*   nbrs = (const int*)d_in[2];
    const float* W1   = (const float*)d_in[3];
    const float* b1   = (const float*)d_in[4];
    const float* W2   = (const float*)d_in[5];
    const float* b2   = (const float*)d_in[6];
    const float* Wd   = (const float*)d_in[7];
    const float* bd   = (const float*)d_in[8];
    float* out = (float*)d_out;

    const int N = in_sizes[0] / FEAT;
    const int E = in_sizes[1];
    if (E <= 0) return;

    const size_t phi_bytes = (size_t)N * OUTF * sizeof(_Float16);
    int egrid = (E + 15) / 16;
    if (egrid > 2048) egrid = 2048;

    if (ws_size >= phi_bytes) {
        // node-level precompute: PHI (N x 384, fp16) in workspace, then edge scale
        dim3 gA((N + 63) / 64);
        phi_kernel<false, true><<<gA, 256, 0, stream>>>(s_j, nbrs, W1, b1, W2, b2, d_ws, N);
        edge_kernel<true><<<egrid, 384, 0, stream>>>(dist, nbrs, d_ws, Wd, bd, out, E, 1);
    } else {
        // fallback: per-edge phi (fp32) directly into d_out, then scale in place
        dim3 gA((E + 63) / 64);
        phi_kernel<true, false><<<gA, 256, 0, stream>>>(s_j, nbrs, W1, b1, W2, b2, d_out, E);
        edge_kernel<false><<<egrid, 384, 0, stream>>>(dist, nbrs, d_out, Wd, bd, out, E, 0);
    }
}

// Round 6
// 354.320 us; speedup vs baseline: 1.7219x; 1.0508x over previous
//
#include <hip/hip_runtime.h>
#include <math.h>

#define FEAT 128
#define OUTF 384
#define NRBF 20

typedef float f32x2 __attribute__((ext_vector_type(2)));
typedef float f32x4 __attribute__((ext_vector_type(4)));
typedef _Float16 f16x4 __attribute__((ext_vector_type(4)));

// Detect whether nbrs buffer is int64 (little-endian: odd int32 words are the
// high halves, all zero since indices < 50000) or genuine int32 pairs.
__device__ __forceinline__ int nbrs_is_i64(const int* nb) {
    int nz = 0;
#pragma unroll
    for (int i = 1; i < 64; i += 2) nz |= nb[i];
    return nz == 0;
}

// Computes PHI[row] = silu(src_row @ W1 + b1) @ W2 + b2 for 64 rows per block.
// GATHER=false: src row i = s_j[i]      (node mode)
// GATHER=true : src row i = s_j[nbrs[i,1]] (direct fallback mode)
// HALF_OUT: store rows as fp16 (node mode) vs fp32 (fallback, dst = d_out).
template <bool GATHER, bool HALF_OUT>
__global__ __launch_bounds__(256) void phi_kernel(
    const float* __restrict__ s_j, const int* __restrict__ nbrs,
    const float* __restrict__ W1, const float* __restrict__ b1,
    const float* __restrict__ W2, const float* __restrict__ b2,
    void* __restrict__ dst_v, int M)
{
    __shared__ __align__(16) float st[FEAT][66]; // transposed tile [k][row]; reused for h
    const int t = threadIdx.x;
    const int base = blockIdx.x * 64;

    int i64f = 0;
    if (GATHER) i64f = nbrs_is_i64(nbrs);

    // stage s tile (transposed). idx consecutive -> k consecutive -> coalesced.
    for (int idx = t; idx < 64 * FEAT; idx += 256) {
        int n = idx >> 7, k = idx & 127;
        int row = base + n;
        float v = 0.f;
        if (row < M) {
            int src = GATHER ? (i64f ? nbrs[4 * (size_t)row + 2] : nbrs[2 * (size_t)row + 1])
                             : row;
            v = s_j[(size_t)src * FEAT + k];
        }
        st[k][n] = v;
    }
    __syncthreads();

    const int cg = t & 31;  // 32 column groups of 4
    const int rg = t >> 5;  // 8 row groups of 8
    const int c0 = cg * 4;
    const int r0 = rg * 8;

    float acc[8][4];
    // ---- h = silu(s @ W1 + b1), thread tile 8 rows x 4 cols ----
    {
        float4 b = *(const float4*)(b1 + c0);
#pragma unroll
        for (int i = 0; i < 8; i++) { acc[i][0] = b.x; acc[i][1] = b.y; acc[i][2] = b.z; acc[i][3] = b.w; }
#pragma unroll 4
        for (int k = 0; k < FEAT; k++) {
            float4 w = *(const float4*)(W1 + (size_t)k * FEAT + c0);
            float2 sa = *(const float2*)(&st[k][r0]);
            float2 sb = *(const float2*)(&st[k][r0 + 2]);
            float2 sc = *(const float2*)(&st[k][r0 + 4]);
            float2 sd = *(const float2*)(&st[k][r0 + 6]);
            float sv[8] = {sa.x, sa.y, sb.x, sb.y, sc.x, sc.y, sd.x, sd.y};
#pragma unroll
            for (int i = 0; i < 8; i++) {
                acc[i][0] += sv[i] * w.x; acc[i][1] += sv[i] * w.y;
                acc[i][2] += sv[i] * w.z; acc[i][3] += sv[i] * w.w;
            }
        }
    }
    __syncthreads();  // all reads of st done before overwriting with h
    // silu + store h transposed into the same LDS buffer
#pragma unroll
    for (int i = 0; i < 8; i++)
#pragma unroll
        for (int j = 0; j < 4; j++) {
            float h = acc[i][j];
            h = h * __frcp_rn(1.f + __expf(-h));
            st[c0 + j][r0 + i] = h;
        }
    __syncthreads();

    // ---- phi = h @ W2 + b2, 3 chunks of 128 cols ----
    for (int ch = 0; ch < 3; ch++) {
        const int oc = ch * 128 + c0;
        float4 b = *(const float4*)(b2 + oc);
#pragma unroll
        for (int i = 0; i < 8; i++) { acc[i][0] = b.x; acc[i][1] = b.y; acc[i][2] = b.z; acc[i][3] = b.w; }
#pragma unroll 4
        for (int k = 0; k < FEAT; k++) {
            float4 w = *(const float4*)(W2 + (size_t)k * OUTF + oc);
            float2 ha = *(const float2*)(&st[k][r0]);
            float2 hb = *(const float2*)(&st[k][r0 + 2]);
            float2 hc = *(const float2*)(&st[k][r0 + 4]);
            float2 hd = *(const float2*)(&st[k][r0 + 6]);
            float hv[8] = {ha.x, ha.y, hb.x, hb.y, hc.x, hc.y, hd.x, hd.y};
#pragma unroll
            for (int i = 0; i < 8; i++) {
                acc[i][0] += hv[i] * w.x; acc[i][1] += hv[i] * w.y;
                acc[i][2] += hv[i] * w.z; acc[i][3] += hv[i] * w.w;
            }
        }
#pragma unroll
        for (int i = 0; i < 8; i++) {
            int row = base + r0 + i;
            if (row < M) {
                if (HALF_OUT) {
                    f16x4 o = {(_Float16)acc[i][0], (_Float16)acc[i][1],
                               (_Float16)acc[i][2], (_Float16)acc[i][3]};
                    *(f16x4*)((_Float16*)dst_v + (size_t)row * OUTF + oc) = o;
                } else {
                    float4 o = {acc[i][0], acc[i][1], acc[i][2], acc[i][3]};
                    *(float4*)((float*)dst_v + (size_t)row * OUTF + oc) = o;
                }
            }
        }
    }
}

// Per edge: out[e] = phi_row * (rbf(dist[e]) @ Wd + bd)
// 96 threads per edge, each owns 4 output cols; Wd column slice (20 x f32x4
// = 80 VGPRs) lives in registers. FOUR consecutive edges per thread per
// iteration: 4 gathers in flight + 4 independent sin-recurrence chains.
// amdgpu_waves_per_eu(3,3) pins the register budget at 168 so the allocator
// keeps wd[] resident instead of chasing 8 waves/EU with spills (r5 showed
// VGPR_Count=64 -> per-iteration wd reload).
// rbf via Chebyshev recurrence: sin((n+1)x) = 2cos(x) sin(nx) - sin((n-1)x).
// FP16PHI: phi rows stored fp16 (node mode, 8 B/lane gather, 768 B rows).
// out written with 16 B NON-TEMPORAL stores.
// NOTE: phi/out may alias (fallback) -> no __restrict__.
template <bool FP16PHI>
__global__ __launch_bounds__(384)
__attribute__((amdgpu_waves_per_eu(3, 3)))
void edge_kernel(
    const float* __restrict__ dist, const int* __restrict__ nbrs,
    const void* phi_v, const float* __restrict__ Wd,
    const float* __restrict__ bd, float* out,
    int E, int gather)
{
    const int g = threadIdx.x / 96;
    const int q = threadIdx.x % 96;
    const int c0 = q * 4;

    f32x4 wd[NRBF];
#pragma unroll
    for (int k = 0; k < NRBF; k++) wd[k] = *(const f32x4*)(Wd + (size_t)k * OUTF + c0);
    f32x4 bdr = *(const f32x4*)(bd + c0);

    int i64f = gather ? nbrs_is_i64(nbrs) : 0;
    const float kx = (float)(M_PI / 5.0);
    const int stride = gridDim.x * 16;

    for (int e = (blockIdx.x * 4 + g) * 4; e < E; e += stride) {
        float d[4];
        int r[4];
#pragma unroll
        for (int j = 0; j < 4; j++) {
            int ej = e + j; if (ej >= E) ej = E - 1;  // clamp (stores guarded)
            d[j] = dist[ej];
            r[j] = gather ? (i64f ? nbrs[4 * (size_t)ej + 2] : nbrs[2 * (size_t)ej + 1]) : ej;
        }
        // issue all 4 gathers before the recurrences
        f32x4 p[4];
#pragma unroll
        for (int j = 0; j < 4; j++) {
            if (FP16PHI) {
                const _Float16* ph = (const _Float16*)phi_v;
                f16x4 h = *(const f16x4*)(ph + (size_t)r[j] * OUTF + c0);
                p[j] = (f32x4){(float)h.x, (float)h.y, (float)h.z, (float)h.w};
            } else {
                const float* pf = (const float*)phi_v;
                p[j] = *(const f32x4*)(pf + (size_t)r[j] * OUTF + c0);
            }
        }

        float t2[4], sp[4], sc[4];
#pragma unroll
        for (int j = 0; j < 4; j++) {
            float x = d[j] * kx;
            sc[j] = __sinf(x);
            t2[j] = 2.f * __cosf(x);
            sp[j] = 0.f;
        }
        f32x4 a[4];
#pragma unroll
        for (int j = 0; j < 4; j++) a[j] = (f32x4){0.f, 0.f, 0.f, 0.f};
#pragma unroll
        for (int n = 0; n < NRBF; n++) {
#pragma unroll
            for (int j = 0; j < 4; j++) {
                a[j] += sc[j] * wd[n];
                float nx = t2[j] * sc[j] - sp[j]; sp[j] = sc[j]; sc[j] = nx;
            }
        }
#pragma unroll
        for (int j = 0; j < 4; j++) {
            if (e + j < E) {
                f32x4 o = p[j] * (a[j] * __frcp_rn(d[j]) + bdr);
                __builtin_nontemporal_store(o, (f32x4*)(out + (size_t)(e + j) * OUTF + c0));
            }
        }
    }
}

extern "C" void kernel_launch(void* const* d_in, const int* in_sizes, int n_in,
                              void* d_out, int out_size, void* d_ws, size_t ws_size,
                              hipStream_t stream)
{
    const float* s_j  = (const float*)d_in[0];
    const float* dist = (const float*)d_in[1];
    const int*   nbrs = (const int*)d_in[2];
    const float* W1   = (const float*)d_in[3];
    const float* b1   = (const float*)d_in[4];
    const float* W2   = (const float*)d_in[5];
    const float* b2   = (const float*)d_in[6];
    const float* Wd   = (const float*)d_in[7];
    const float* bd   = (const float*)d_in[8];
    float* out = (float*)d_out;

    const int N = in_sizes[0] / FEAT;
    const int E = in_sizes[1];
    if (E <= 0) return;

    const size_t phi_bytes = (size_t)N * OUTF * sizeof(_Float16);
    int egrid = (E + 15) / 16;
    if (egrid > 2048) egrid = 2048;

    if (ws_size >= phi_bytes) {
        // node-level precompute: PHI (N x 384, fp16) in workspace, then edge scale
        dim3 gA((N + 63) / 64);
        phi_kernel<false, true><<<gA, 256, 0, stream>>>(s_j, nbrs, W1, b1, W2, b2, d_ws, N);
        edge_kernel<true><<<egrid, 384, 0, stream>>>(dist, nbrs, d_ws, Wd, bd, out, E, 1);
    } else {
        // fallback: per-edge phi (fp32) directly into d_out, then scale in place
        dim3 gA((E + 63) / 64);
        phi_kernel<true, false><<<gA, 256, 0, stream>>>(s_j, nbrs, W1, b1, W2, b2, d_out, E);
        edge_kernel<false><<<egrid, 384, 0, stream>>>(dist, nbrs, d_out, Wd, bd, out, E, 0);
    }
}

// Round 7
// 354.229 us; speedup vs baseline: 1.7223x; 1.0003x over previous
//
#include <hip/hip_runtime.h>
#include <math.h>

#define FEAT 128
#define OUTF 384
#define NRBF 20
#define EILP 8

typedef float f32x2 __attribute__((ext_vector_type(2)));
typedef float f32x4 __attribute__((ext_vector_type(4)));
typedef _Float16 f16x4 __attribute__((ext_vector_type(4)));

// Detect whether nbrs buffer is int64 (little-endian: odd int32 words are the
// high halves, all zero since indices < 50000) or genuine int32 pairs.
__device__ __forceinline__ int nbrs_is_i64(const int* nb) {
    int nz = 0;
#pragma unroll
    for (int i = 1; i < 64; i += 2) nz |= nb[i];
    return nz == 0;
}

// Computes PHI[row] = silu(src_row @ W1 + b1) @ W2 + b2 for 64 rows per block.
// GATHER=false: src row i = s_j[i]      (node mode)
// GATHER=true : src row i = s_j[nbrs[i,1]] (direct fallback mode)
// HALF_OUT: store rows as fp16 (node mode) vs fp32 (fallback, dst = d_out).
template <bool GATHER, bool HALF_OUT>
__global__ __launch_bounds__(256) void phi_kernel(
    const float* __restrict__ s_j, const int* __restrict__ nbrs,
    const float* __restrict__ W1, const float* __restrict__ b1,
    const float* __restrict__ W2, const float* __restrict__ b2,
    void* __restrict__ dst_v, int M)
{
    __shared__ __align__(16) float st[FEAT][66]; // transposed tile [k][row]; reused for h
    const int t = threadIdx.x;
    const int base = blockIdx.x * 64;

    int i64f = 0;
    if (GATHER) i64f = nbrs_is_i64(nbrs);

    // stage s tile (transposed). idx consecutive -> k consecutive -> coalesced.
    for (int idx = t; idx < 64 * FEAT; idx += 256) {
        int n = idx >> 7, k = idx & 127;
        int row = base + n;
        float v = 0.f;
        if (row < M) {
            int src = GATHER ? (i64f ? nbrs[4 * (size_t)row + 2] : nbrs[2 * (size_t)row + 1])
                             : row;
            v = s_j[(size_t)src * FEAT + k];
        }
        st[k][n] = v;
    }
    __syncthreads();

    const int cg = t & 31;  // 32 column groups of 4
    const int rg = t >> 5;  // 8 row groups of 8
    const int c0 = cg * 4;
    const int r0 = rg * 8;

    float acc[8][4];
    // ---- h = silu(s @ W1 + b1), thread tile 8 rows x 4 cols ----
    {
        float4 b = *(const float4*)(b1 + c0);
#pragma unroll
        for (int i = 0; i < 8; i++) { acc[i][0] = b.x; acc[i][1] = b.y; acc[i][2] = b.z; acc[i][3] = b.w; }
#pragma unroll 4
        for (int k = 0; k < FEAT; k++) {
            float4 w = *(const float4*)(W1 + (size_t)k * FEAT + c0);
            float2 sa = *(const float2*)(&st[k][r0]);
            float2 sb = *(const float2*)(&st[k][r0 + 2]);
            float2 sc = *(const float2*)(&st[k][r0 + 4]);
            float2 sd = *(const float2*)(&st[k][r0 + 6]);
            float sv[8] = {sa.x, sa.y, sb.x, sb.y, sc.x, sc.y, sd.x, sd.y};
#pragma unroll
            for (int i = 0; i < 8; i++) {
                acc[i][0] += sv[i] * w.x; acc[i][1] += sv[i] * w.y;
                acc[i][2] += sv[i] * w.z; acc[i][3] += sv[i] * w.w;
            }
        }
    }
    __syncthreads();  // all reads of st done before overwriting with h
    // silu + store h transposed into the same LDS buffer
#pragma unroll
    for (int i = 0; i < 8; i++)
#pragma unroll
        for (int j = 0; j < 4; j++) {
            float h = acc[i][j];
            h = h * __frcp_rn(1.f + __expf(-h));
            st[c0 + j][r0 + i] = h;
        }
    __syncthreads();

    // ---- phi = h @ W2 + b2, 3 chunks of 128 cols ----
    for (int ch = 0; ch < 3; ch++) {
        const int oc = ch * 128 + c0;
        float4 b = *(const float4*)(b2 + oc);
#pragma unroll
        for (int i = 0; i < 8; i++) { acc[i][0] = b.x; acc[i][1] = b.y; acc[i][2] = b.z; acc[i][3] = b.w; }
#pragma unroll 4
        for (int k = 0; k < FEAT; k++) {
            float4 w = *(const float4*)(W2 + (size_t)k * OUTF + oc);
            float2 ha = *(const float2*)(&st[k][r0]);
            float2 hb = *(const float2*)(&st[k][r0 + 2]);
            float2 hc = *(const float2*)(&st[k][r0 + 4]);
            float2 hd = *(const float2*)(&st[k][r0 + 6]);
            float hv[8] = {ha.x, ha.y, hb.x, hb.y, hc.x, hc.y, hd.x, hd.y};
#pragma unroll
            for (int i = 0; i < 8; i++) {
                acc[i][0] += hv[i] * w.x; acc[i][1] += hv[i] * w.y;
                acc[i][2] += hv[i] * w.z; acc[i][3] += hv[i] * w.w;
            }
        }
#pragma unroll
        for (int i = 0; i < 8; i++) {
            int row = base + r0 + i;
            if (row < M) {
                if (HALF_OUT) {
                    f16x4 o = {(_Float16)acc[i][0], (_Float16)acc[i][1],
                               (_Float16)acc[i][2], (_Float16)acc[i][3]};
                    *(f16x4*)((_Float16*)dst_v + (size_t)row * OUTF + oc) = o;
                } else {
                    float4 o = {acc[i][0], acc[i][1], acc[i][2], acc[i][3]};
                    *(float4*)((float*)dst_v + (size_t)row * OUTF + oc) = o;
                }
            }
        }
    }
}

// Per edge: out[e] = phi_row * (rbf(dist[e]) @ Wd + bd)
// 96 threads per edge, each owns 4 output cols. Wd column slices live in LDS
// (30 KB, staged once, stride-16B ds_read_b128 = conflict-free, one read per
// n shared across all 8 in-flight edges) instead of 80 VGPRs — the freed
// registers buy EIGHT edges of ILP per thread (~24 gathers in flight/SIMD,
// 8 independent recurrence chains).
// rbf via Chebyshev recurrence: sin((n+1)x) = 2cos(x) sin(nx) - sin((n-1)x).
// FP16PHI: phi rows stored fp16 (node mode, 8 B/lane gather, 768 B rows).
// out written with 16 B NON-TEMPORAL stores.
// NOTE: phi/out may alias (fallback) -> no __restrict__.
template <bool FP16PHI>
__global__ __launch_bounds__(384)
__attribute__((amdgpu_waves_per_eu(3, 3)))
void edge_kernel(
    const float* __restrict__ dist, const int* __restrict__ nbrs,
    const void* phi_v, const float* __restrict__ Wd,
    const float* __restrict__ bd, float* out,
    int E, int gather)
{
    __shared__ __align__(16) f32x4 wdl[NRBF][96];
    const int t = threadIdx.x;
    for (int idx = t; idx < NRBF * 96; idx += 384) {
        int n = idx / 96, qq = idx % 96;
        wdl[n][qq] = *(const f32x4*)(Wd + (size_t)n * OUTF + qq * 4);
    }
    __syncthreads();

    const int g = t / 96;
    const int q = t % 96;
    const int c0 = q * 4;

    f32x4 bdr = *(const f32x4*)(bd + c0);

    int i64f = gather ? nbrs_is_i64(nbrs) : 0;
    const float kx = (float)(M_PI / 5.0);
    const int stride = gridDim.x * (4 * EILP);

    for (int e = (blockIdx.x * 4 + g) * EILP; e < E; e += stride) {
        float d[EILP];
        int r[EILP];
#pragma unroll
        for (int j = 0; j < EILP; j++) {
            int ej = e + j; if (ej >= E) ej = E - 1;  // clamp (stores guarded)
            d[j] = dist[ej];
            r[j] = gather ? (i64f ? nbrs[4 * (size_t)ej + 2] : nbrs[2 * (size_t)ej + 1]) : ej;
        }
        // issue all gathers before the recurrences
        f32x4 p[EILP];
#pragma unroll
        for (int j = 0; j < EILP; j++) {
            if (FP16PHI) {
                const _Float16* ph = (const _Float16*)phi_v;
                f16x4 h = *(const f16x4*)(ph + (size_t)r[j] * OUTF + c0);
                p[j] = (f32x4){(float)h.x, (float)h.y, (float)h.z, (float)h.w};
            } else {
                const float* pf = (const float*)phi_v;
                p[j] = *(const f32x4*)(pf + (size_t)r[j] * OUTF + c0);
            }
        }

        float t2[EILP], sp[EILP], sc[EILP];
#pragma unroll
        for (int j = 0; j < EILP; j++) {
            float s, c;
            __sincosf(d[j] * kx, &s, &c);
            sc[j] = s;
            t2[j] = 2.f * c;
            sp[j] = 0.f;
        }
        f32x4 a[EILP];
#pragma unroll
        for (int j = 0; j < EILP; j++) a[j] = (f32x4){0.f, 0.f, 0.f, 0.f};
#pragma unroll
        for (int n = 0; n < NRBF; n++) {
            f32x4 w = wdl[n][q];
#pragma unroll
            for (int j = 0; j < EILP; j++) {
                a[j] += sc[j] * w;
                float nx = t2[j] * sc[j] - sp[j]; sp[j] = sc[j]; sc[j] = nx;
            }
        }
#pragma unroll
        for (int j = 0; j < EILP; j++) {
            if (e + j < E) {
                f32x4 o = p[j] * (a[j] * __frcp_rn(d[j]) + bdr);
                __builtin_nontemporal_store(o, (f32x4*)(out + (size_t)(e + j) * OUTF + c0));
            }
        }
    }
}

extern "C" void kernel_launch(void* const* d_in, const int* in_sizes, int n_in,
                              void* d_out, int out_size, void* d_ws, size_t ws_size,
                              hipStream_t stream)
{
    const float* s_j  = (const float*)d_in[0];
    const float* dist = (const float*)d_in[1];
    const int*   nbrs = (const int*)d_in[2];
    const float* W1   = (const float*)d_in[3];
    const float* b1   = (const float*)d_in[4];
    const float* W2   = (const float*)d_in[5];
    const float* b2   = (const float*)d_in[6];
    const float* Wd   = (const float*)d_in[7];
    const float* bd   = (const float*)d_in[8];
    float* out = (float*)d_out;

    const int N = in_sizes[0] / FEAT;
    const int E = in_sizes[1];
    if (E <= 0) return;

    const size_t phi_bytes = (size_t)N * OUTF * sizeof(_Float16);
    int egrid = (E + 4 * EILP - 1) / (4 * EILP);
    if (egrid > 2048) egrid = 2048;

    if (ws_size >= phi_bytes) {
        // node-level precompute: PHI (N x 384, fp16) in workspace, then edge scale
        dim3 gA((N + 63) / 64);
        phi_kernel<false, true><<<gA, 256, 0, stream>>>(s_j, nbrs, W1, b1, W2, b2, d_ws, N);
        edge_kernel<true><<<egrid, 384, 0, stream>>>(dist, nbrs, d_ws, Wd, bd, out, E, 1);
    } else {
        // fallback: per-edge phi (fp32) directly into d_out, then scale in place
        dim3 gA((E + 63) / 64);
        phi_kernel<true, false><<<gA, 256, 0, stream>>>(s_j, nbrs, W1, b1, W2, b2, d_out, E);
        edge_kernel<false><<<egrid, 384, 0, stream>>>(dist, nbrs, d_out, Wd, bd, out, E, 0);
    }
}

// Round 9
// 277.449 us; speedup vs baseline: 2.1990x; 1.2767x over previous
//
#include <hip/hip_runtime.h>
#include <math.h>

#define FEAT 128
#define OUTF 384
#define NRBF 20
#define EILP 8

typedef float f32x2 __attribute__((ext_vector_type(2)));
typedef float f32x4 __attribute__((ext_vector_type(4)));
typedef _Float16 f16x4 __attribute__((ext_vector_type(4)));
typedef _Float16 f16x8 __attribute__((ext_vector_type(8)));

// Detect whether nbrs buffer is int64 (little-endian: odd int32 words are the
// high halves, all zero since indices < 50000) or genuine int32 pairs.
__device__ __forceinline__ int nbrs_is_i64(const int* nb) {
    int nz = 0;
#pragma unroll
    for (int i = 1; i < 64; i += 2) nz |= nb[i];
    return nz == 0;
}

// ---------------------------------------------------------------------------
// Convert W1 (128x128) and W2 (128x384) to f16 in MFMA B-fragment order:
// frag (ct, ks, lane) holds 8 f16: W[ks*32 + (lane>>4)*8 + j][ct*16 + (lane&15)]
// so the GEMM kernel does ONE coalesced 16 B load per fragment per lane.
__global__ __launch_bounds__(256) void prep_w_kernel(
    const float* __restrict__ W1, const float* __restrict__ W2,
    _Float16* __restrict__ w1f, _Float16* __restrict__ w2f)
{
    int idx = blockIdx.x * 256 + threadIdx.x;
    if (idx < 8 * 4 * 64) {                 // W1: 8 col-tiles x 4 k-steps
        int ct = idx >> 8, ks = (idx >> 6) & 3, lane = idx & 63;
        int lcol = lane & 15, lgrp = lane >> 4;
        _Float16* dst = w1f + (size_t)idx * 8;
        const float* src = W1 + (size_t)(ks * 32 + lgrp * 8) * FEAT + ct * 16 + lcol;
#pragma unroll
        for (int j = 0; j < 8; j++) dst[j] = (_Float16)src[(size_t)j * FEAT];
    } else {
        int i2 = idx - 2048;
        if (i2 < 24 * 4 * 64) {             // W2: 24 col-tiles x 4 k-steps
            int ct = i2 >> 8, ks = (i2 >> 6) & 3, lane = i2 & 63;
            int lcol = lane & 15, lgrp = lane >> 4;
            _Float16* dst = w2f + (size_t)i2 * 8;
            const float* src = W2 + (size_t)(ks * 32 + lgrp * 8) * OUTF + ct * 16 + lcol;
#pragma unroll
            for (int j = 0; j < 8; j++) dst[j] = (_Float16)src[(size_t)j * OUTF];
        }
    }
}

// ---------------------------------------------------------------------------
// MFMA phi: PHI[row] = (silu(s_j[row] @ W1 + b1) @ W2 + b2) as fp16.
// 64 rows/block, 256 threads = 4 waves; wave w owns rows [w*16, w*16+16).
// mfma_f32_16x16x32_f16 layouts: A: row=lane&15, k=(lane>>4)*8+j;
// B: col=lane&15, same k; D: col=lane&15, row=(lane>>4)*4+reg.
// H is wave-private in LDS between the GEMMs (no extra __syncthreads).
__global__ __launch_bounds__(256) void phi_mfma_kernel(
    const float* __restrict__ s_j,
    const _Float16* __restrict__ w1f, const float* __restrict__ b1,
    const _Float16* __restrict__ w2f, const float* __restrict__ b2,
    _Float16* __restrict__ PHI, int M)
{
    __shared__ __align__(16) float s32[64][136];        // padded: 4-way max on b128
    __shared__ __align__(16) _Float16 h16[4][16][144];  // wave-private H / PHI-chunk
    const int t = threadIdx.x;
    const int base = blockIdx.x * 64;

    // stage s_j tile f32, coalesced float4
    for (int idx = t; idx < 64 * 32; idx += 256) {
        int row = idx >> 5, c4 = (idx & 31) * 4;
        float4 v = {0.f, 0.f, 0.f, 0.f};
        if (base + row < M) v = *(const float4*)(s_j + (size_t)(base + row) * FEAT + c4);
        *(float4*)&s32[row][c4] = v;
    }
    __syncthreads();

    const int w = t >> 6, lane = t & 63;
    const int lcol = lane & 15;      // A-row / B-col / D-col
    const int lgrp = lane >> 4;      // k-group (inputs) / row-group (D)
    const int r0 = w * 16;

    // A1 fragments (rows of s tile, f32 -> f16)
    f16x8 a1[4];
#pragma unroll
    for (int ks = 0; ks < 4; ks++) {
        const float* p = &s32[r0 + lcol][ks * 32 + lgrp * 8];
        float4 u = *(const float4*)p;
        float4 v = *(const float4*)(p + 4);
        a1[ks] = (f16x8){(_Float16)u.x, (_Float16)u.y, (_Float16)u.z, (_Float16)u.w,
                         (_Float16)v.x, (_Float16)v.y, (_Float16)v.z, (_Float16)v.w};
    }

    // ---- GEMM1: H = silu(S @ W1 + b1) -> h16 ----
#pragma unroll
    for (int ct = 0; ct < 8; ct++) {
        float bb = b1[ct * 16 + lcol];
        f32x4 acc = {bb, bb, bb, bb};
#pragma unroll
        for (int ks = 0; ks < 4; ks++) {
            f16x8 b = *(const f16x8*)(w1f + ((size_t)(ct * 4 + ks) * 64 + lane) * 8);
            acc = __builtin_amdgcn_mfma_f32_16x16x32_f16(a1[ks], b, acc, 0, 0, 0);
        }
#pragma unroll
        for (int r = 0; r < 4; r++) {
            float h = acc[r];
            h = h * __frcp_rn(1.f + __expf(-h));
            h16[w][lgrp * 4 + r][ct * 16 + lcol] = (_Float16)h;
        }
    }

    // A2 fragments from H (load all before h16 is reused as output staging)
    f16x8 a2[4];
#pragma unroll
    for (int ks = 0; ks < 4; ks++)
        a2[ks] = *(const f16x8*)&h16[w][lcol][ks * 32 + lgrp * 8];

    // ---- GEMM2: PHI = H @ W2 + b2, 3 chunks of 128 cols (24 col-tiles) ----
    for (int ch = 0; ch < 3; ch++) {
#pragma unroll
        for (int c8 = 0; c8 < 8; c8++) {
            int ct = ch * 8 + c8;
            float bb = b2[ct * 16 + lcol];
            f32x4 acc = {bb, bb, bb, bb};
#pragma unroll
            for (int ks = 0; ks < 4; ks++) {
                f16x8 b = *(const f16x8*)(w2f + ((size_t)(ct * 4 + ks) * 64 + lane) * 8);
                acc = __builtin_amdgcn_mfma_f32_16x16x32_f16(a2[ks], b, acc, 0, 0, 0);
            }
#pragma unroll
            for (int r = 0; r < 4; r++)
                h16[w][lgrp * 4 + r][c8 * 16 + lcol] = (_Float16)acc[r];
        }
        // dump 16x128 chunk, coalesced 16 B f16 stores
#pragma unroll
        for (int i = 0; i < 4; i++) {
            int flat = i * 64 + lane;
            int row = flat >> 4, cc = (flat & 15) * 8;
            int grow = base + r0 + row;
            if (grow < M) {
                f16x8 v = *(const f16x8*)&h16[w][row][cc];
                *(f16x8*)(PHI + (size_t)grow * OUTF + ch * 128 + cc) = v;
            }
        }
    }
}

// ---------------------------------------------------------------------------
// Scalar fp32 phi (FALLBACK ONLY: per-edge, dst = d_out fp32)
template <bool GATHER, bool HALF_OUT>
__global__ __launch_bounds__(256) void phi_kernel(
    const float* __restrict__ s_j, const int* __restrict__ nbrs,
    const float* __restrict__ W1, const float* __restrict__ b1,
    const float* __restrict__ W2, const float* __restrict__ b2,
    void* __restrict__ dst_v, int M)
{
    __shared__ __align__(16) float st[FEAT][66];
    const int t = threadIdx.x;
    const int base = blockIdx.x * 64;

    int i64f = 0;
    if (GATHER) i64f = nbrs_is_i64(nbrs);

    for (int idx = t; idx < 64 * FEAT; idx += 256) {
        int n = idx >> 7, k = idx & 127;
        int row = base + n;
        float v = 0.f;
        if (row < M) {
            int src = GATHER ? (i64f ? nbrs[4 * (size_t)row + 2] : nbrs[2 * (size_t)row + 1])
                             : row;
            v = s_j[(size_t)src * FEAT + k];
        }
        st[k][n] = v;
    }
    __syncthreads();

    const int cg = t & 31, rg = t >> 5;
    const int c0 = cg * 4, r0 = rg * 8;

    float acc[8][4];
    {
        float4 b = *(const float4*)(b1 + c0);
#pragma unroll
        for (int i = 0; i < 8; i++) { acc[i][0] = b.x; acc[i][1] = b.y; acc[i][2] = b.z; acc[i][3] = b.w; }
#pragma unroll 4
        for (int k = 0; k < FEAT; k++) {
            float4 w = *(const float4*)(W1 + (size_t)k * FEAT + c0);
            float2 sa = *(const float2*)(&st[k][r0]);
            float2 sb = *(const float2*)(&st[k][r0 + 2]);
            float2 sc = *(const float2*)(&st[k][r0 + 4]);
            float2 sd = *(const float2*)(&st[k][r0 + 6]);
            float sv[8] = {sa.x, sa.y, sb.x, sb.y, sc.x, sc.y, sd.x, sd.y};
#pragma unroll
            for (int i = 0; i < 8; i++) {
                acc[i][0] += sv[i] * w.x; acc[i][1] += sv[i] * w.y;
                acc[i][2] += sv[i] * w.z; acc[i][3] += sv[i] * w.w;
            }
        }
    }
    __syncthreads();
#pragma unroll
    for (int i = 0; i < 8; i++)
#pragma unroll
        for (int j = 0; j < 4; j++) {
            float h = acc[i][j];
            h = h * __frcp_rn(1.f + __expf(-h));
            st[c0 + j][r0 + i] = h;
        }
    __syncthreads();

    for (int ch = 0; ch < 3; ch++) {
        const int oc = ch * 128 + c0;
        float4 b = *(const float4*)(b2 + oc);
#pragma unroll
        for (int i = 0; i < 8; i++) { acc[i][0] = b.x; acc[i][1] = b.y; acc[i][2] = b.z; acc[i][3] = b.w; }
#pragma unroll 4
        for (int k = 0; k < FEAT; k++) {
            float4 w = *(const float4*)(W2 + (size_t)k * OUTF + oc);
            float2 ha = *(const float2*)(&st[k][r0]);
            float2 hb = *(const float2*)(&st[k][r0 + 2]);
            float2 hc = *(const float2*)(&st[k][r0 + 4]);
            float2 hd = *(const float2*)(&st[k][r0 + 6]);
            float hv[8] = {ha.x, ha.y, hb.x, hb.y, hc.x, hc.y, hd.x, hd.y};
#pragma unroll
            for (int i = 0; i < 8; i++) {
                acc[i][0] += hv[i] * w.x; acc[i][1] += hv[i] * w.y;
                acc[i][2] += hv[i] * w.z; acc[i][3] += hv[i] * w.w;
            }
        }
#pragma unroll
        for (int i = 0; i < 8; i++) {
            int row = base + r0 + i;
            if (row < M) {
                if (HALF_OUT) {
                    f16x4 o = {(_Float16)acc[i][0], (_Float16)acc[i][1],
                               (_Float16)acc[i][2], (_Float16)acc[i][3]};
                    *(f16x4*)((_Float16*)dst_v + (size_t)row * OUTF + oc) = o;
                } else {
                    float4 o = {acc[i][0], acc[i][1], acc[i][2], acc[i][3]};
                    *(float4*)((float*)dst_v + (size_t)row * OUTF + oc) = o;
                }
            }
        }
    }
}

// ---------------------------------------------------------------------------
// Per edge: out[e] = phi_row * (rbf(dist[e]) @ Wd + bd)
// 96 threads/edge x 4 cols; Wd in LDS; 8 edges of ILP per thread.
template <bool FP16PHI>
__global__ __launch_bounds__(384)
__attribute__((amdgpu_waves_per_eu(3, 3)))
void edge_kernel(
    const float* __restrict__ dist, const int* __restrict__ nbrs,
    const void* phi_v, const float* __restrict__ Wd,
    const float* __restrict__ bd, float* out,
    int E, int gather)
{
    __shared__ __align__(16) f32x4 wdl[NRBF][96];
    const int t = threadIdx.x;
    for (int idx = t; idx < NRBF * 96; idx += 384) {
        int n = idx / 96, qq = idx % 96;
        wdl[n][qq] = *(const f32x4*)(Wd + (size_t)n * OUTF + qq * 4);
    }
    __syncthreads();

    const int g = t / 96;
    const int q = t % 96;
    const int c0 = q * 4;

    f32x4 bdr = *(const f32x4*)(bd + c0);

    int i64f = gather ? nbrs_is_i64(nbrs) : 0;
    const float kx = (float)(M_PI / 5.0);
    const int stride = gridDim.x * (4 * EILP);

    for (int e = (blockIdx.x * 4 + g) * EILP; e < E; e += stride) {
        float d[EILP];
        int r[EILP];
#pragma unroll
        for (int j = 0; j < EILP; j++) {
            int ej = e + j; if (ej >= E) ej = E - 1;
            d[j] = dist[ej];
            r[j] = gather ? (i64f ? nbrs[4 * (size_t)ej + 2] : nbrs[2 * (size_t)ej + 1]) : ej;
        }
        f32x4 p[EILP];
#pragma unroll
        for (int j = 0; j < EILP; j++) {
            if (FP16PHI) {
                const _Float16* ph = (const _Float16*)phi_v;
                f16x4 h = *(const f16x4*)(ph + (size_t)r[j] * OUTF + c0);
                p[j] = (f32x4){(float)h.x, (float)h.y, (float)h.z, (float)h.w};
            } else {
                const float* pf = (const float*)phi_v;
                p[j] = *(const f32x4*)(pf + (size_t)r[j] * OUTF + c0);
            }
        }

        float t2[EILP], sp[EILP], sc[EILP];
#pragma unroll
        for (int j = 0; j < EILP; j++) {
            float s, c;
            __sincosf(d[j] * kx, &s, &c);
            sc[j] = s;
            t2[j] = 2.f * c;
            sp[j] = 0.f;
        }
        f32x4 a[EILP];
#pragma unroll
        for (int j = 0; j < EILP; j++) a[j] = (f32x4){0.f, 0.f, 0.f, 0.f};
#pragma unroll
        for (int n = 0; n < NRBF; n++) {
            f32x4 w = wdl[n][q];
#pragma unroll
            for (int j = 0; j < EILP; j++) {
                a[j] += sc[j] * w;
                float nx = t2[j] * sc[j] - sp[j]; sp[j] = sc[j]; sc[j] = nx;
            }
        }
#pragma unroll
        for (int j = 0; j < EILP; j++) {
            if (e + j < E) {
                f32x4 o = p[j] * (a[j] * __frcp_rn(d[j]) + bdr);
                __builtin_nontemporal_store(o, (f32x4*)(out + (size_t)(e + j) * OUTF + c0));
            }
        }
    }
}

extern "C" void kernel_launch(void* const* d_in, const int* in_sizes, int n_in,
                              void* d_out, int out_size, void* d_ws, size_t ws_size,
                              hipStream_t stream)
{
    const float* s_j  = (const float*)d_in[0];
    const float* dist = (const float*)d_in[1];
    const int*   nbrs = (const int*)d_in[2];
    const float* W1   = (const float*)d_in[3];
    const float* b1   = (const float*)d_in[4];
    const float* W2   = (const float*)d_in[5];
    const float* b2   = (const float*)d_in[6];
    const float* Wd   = (const float*)d_in[7];
    const float* bd   = (const float*)d_in[8];
    float* out = (float*)d_out;

    const int N = in_sizes[0] / FEAT;
    const int E = in_sizes[1];
    if (E <= 0) return;

    const size_t phi_bytes = (size_t)N * OUTF * sizeof(_Float16);
    const size_t w1_off = phi_bytes;                        // 16B-aligned
    const size_t w2_off = w1_off + (size_t)8 * 4 * 64 * 8 * 2;
    const size_t need   = w2_off + (size_t)24 * 4 * 64 * 8 * 2;

    int egrid = (E + 4 * EILP - 1) / (4 * EILP);
    if (egrid > 2048) egrid = 2048;

    if (ws_size >= need) {
        _Float16* PHI = (_Float16*)d_ws;
        _Float16* w1f = (_Float16*)((char*)d_ws + w1_off);
        _Float16* w2f = (_Float16*)((char*)d_ws + w2_off);
        prep_w_kernel<<<32, 256, 0, stream>>>(W1, W2, w1f, w2f);
        phi_mfma_kernel<<<(N + 63) / 64, 256, 0, stream>>>(s_j, w1f, b1, w2f, b2, PHI, N);
        edge_kernel<true><<<egrid, 384, 0, stream>>>(dist, nbrs, PHI, Wd, bd, out, E, 1);
    } else {
        // fallback: per-edge fp32 phi directly into d_out, then scale in place
        dim3 gA((E + 63) / 64);
        phi_kernel<true, false><<<gA, 256, 0, stream>>>(s_j, nbrs, W1, b1, W2, b2, d_out, E);
        edge_kernel<false><<<egrid, 384, 0, stream>>>(dist, nbrs, d_out, Wd, bd, out, E, 0);
    }
}